// Round 9
// baseline (821.364 us; speedup 1.0000x reference)
//
#include <hip/hip_runtime.h>

#define N_GRID 144
#define INV_DX 128.0f
#define NSUPER 4096          // 16 x 16 x 16 superbins of 8^3 cells
#define SCAN_THREADS 1024
#define PER_THREAD 4         // 1024 * 4 = 4096
#define KP 8                 // particles per thread in streaming passes

__device__ __forceinline__ int sbin_of(float px, float py, float pz) {
    int bx = (int)(px * INV_DX);   // 0..127
    int by = (int)(py * INV_DX);
    int bz = (int)(pz * INV_DX);
    return ((bx >> 3) << 8) | ((by >> 3) << 4) | (bz >> 3);   // 12-bit key
}

// Pass 0: bin12[i] = superbin key (coalesced, no atomics)
__global__ void __launch_bounds__(256) binify_kernel(
    const float* __restrict__ pos, unsigned short* __restrict__ bin12, int n)
{
    int base = blockIdx.x * (blockDim.x * KP) + threadIdx.x;
#pragma unroll
    for (int k = 0; k < KP; ++k) {
        int p = base + k * 256;
        if (p < n) {
            float px = pos[3 * p + 0];
            float py = pos[3 * p + 1];
            float pz = pos[3 * p + 2];
            bin12[p] = (unsigned short)sbin_of(px, py, pz);
        }
    }
}

// Pass 1: octant-filtered histogram; each XCD's atomics hit a private 2KB
// slice of the 16KB table (key>>9 = x-octant).
__global__ void __launch_bounds__(256) hist8_kernel(
    const unsigned short* __restrict__ bin12, unsigned int* __restrict__ hist, int n)
{
    int owner = blockIdx.x & 7;
    int chunk = blockIdx.x >> 3;
    int base = chunk * (256 * KP) + threadIdx.x;
    int bn[KP], ok[KP];
#pragma unroll
    for (int k = 0; k < KP; ++k) {
        int p = base + k * 256;
        ok[k] = (p < n);
        bn[k] = bin12[ok[k] ? p : 0];
        ok[k] = ok[k] && ((bn[k] >> 9) == owner);
    }
#pragma unroll
    for (int k = 0; k < KP; ++k) {
        if (ok[k]) atomicAdd(&hist[bn[k]], 1u);
    }
}

__global__ void __launch_bounds__(SCAN_THREADS) scan_kernel(
    const unsigned int* __restrict__ hist, unsigned int* __restrict__ offs)
{
    __shared__ unsigned int partial[SCAN_THREADS];
    int t = threadIdx.x;
    unsigned int local[PER_THREAD];
    unsigned int s = 0;
    int base = t * PER_THREAD;
#pragma unroll
    for (int k = 0; k < PER_THREAD; ++k) {
        local[k] = s;
        s += hist[base + k];
    }
    partial[t] = s;
    __syncthreads();
    for (int d = 1; d < SCAN_THREADS; d <<= 1) {
        unsigned int v = (t >= d) ? partial[t - d] : 0u;
        __syncthreads();
        partial[t] += v;
        __syncthreads();
    }
    unsigned int chunk_excl = (t == 0) ? 0u : partial[t - 1];
#pragma unroll
    for (int k = 0; k < PER_THREAD; ++k)
        offs[base + k] = chunk_excl + local[k];
}

// Pass 2: octant-filtered coarse scatter. Writers of any coarse[] line are
// same-XCD (filter) AND temporally dense (coarse bins: ~450ns per line fill)
// -> partial 16B stores merge in L2 before writeback.
__global__ void __launch_bounds__(256) scatter8_kernel(
    const float* __restrict__ pos, const unsigned short* __restrict__ bin12,
    float4* __restrict__ coarse, unsigned int* __restrict__ offs, int n)
{
    int owner = blockIdx.x & 7;
    int chunk = blockIdx.x >> 3;
    int base = chunk * (256 * KP) + threadIdx.x;
    float px[KP], py[KP], pz[KP];
    int bn[KP], ok[KP];
#pragma unroll
    for (int k = 0; k < KP; ++k) {
        int p = base + k * 256;
        ok[k] = (p < n);
        int q = ok[k] ? p : 0;
        px[k] = pos[3 * q + 0];
        py[k] = pos[3 * q + 1];
        pz[k] = pos[3 * q + 2];
        bn[k] = bin12[q];
        ok[k] = ok[k] && ((bn[k] >> 9) == owner);
    }
    unsigned int off[KP];
#pragma unroll
    for (int k = 0; k < KP; ++k) {
        if (ok[k]) off[k] = atomicAdd(&offs[bn[k]], 1u);
    }
#pragma unroll
    for (int k = 0; k < KP; ++k) {
        if (ok[k]) {
            int p = base + k * 256;
            float4 v;
            v.x = px[k]; v.y = py[k]; v.z = pz[k];
            v.w = __int_as_float(p);
            coarse[off[k]] = v;
        }
    }
}

// Pass 3: fused gather. One block per superbin; stencil = 10^3 nodes x3 =
// 3000 floats (12KB LDS) staged once; particles (unsorted within superbin)
// read coalesced from coarse[], 27 taps served from LDS. Octant-swizzled so
// each XCD reads a ~4.4MB x-slab of grid (L2-fit).
__global__ void __launch_bounds__(256) gather_super_kernel(
    const float* __restrict__ grid,
    const float4* __restrict__ coarse,
    const unsigned int* __restrict__ offs_end,
    const unsigned int* __restrict__ hist,
    float* __restrict__ out)
{
    int s = (blockIdx.x & 7) * 512 + (blockIdx.x >> 3);   // bijective, 4096=8*512

    unsigned int end = offs_end[s];
    unsigned int cnt = hist[s];
    if (cnt == 0) return;
    unsigned int start = end - cnt;

    int obx = 8 * (s >> 8);
    int oby = 8 * ((s >> 4) & 15);
    int obz = 8 * (s & 15);

    const int s1 = N_GRID * 3;
    const int s0 = N_GRID * N_GRID * 3;

    __shared__ float R[3000];          // [10][10][30]
    const float* gorig = grid + (long)obx * s0 + oby * s1 + obz * 3;
    int tid = threadIdx.x;
    for (int f = tid; f < 3000; f += 256) {
        int row = f / 30;              // x*10 + y
        int zz = f - row * 30;
        R[f] = gorig[(row / 10) * s0 + (row % 10) * s1 + zz];
    }
    __syncthreads();

    for (unsigned int j = start + tid; j < end; j += 256) {
        float4 p = coarse[j];
        int idx = __float_as_int(p.w);

        float nx = p.x * INV_DX;
        float ny = p.y * INV_DX;
        float nz = p.z * INV_DX;
        int bx = (int)nx;
        int by = (int)ny;
        int bz = (int)nz;
        float lx = nx - (float)bx;
        float ly = ny - (float)by;
        float lz = nz - (float)bz;

        float wx[3], wy[3], wz[3];
        wx[0] = 0.5f * (1.0f - lx) * (1.0f - lx);
        wx[1] = 0.75f - (0.5f - lx) * (0.5f - lx);
        wx[2] = 0.5f * lx * lx;
        wy[0] = 0.5f * (1.0f - ly) * (1.0f - ly);
        wy[1] = 0.75f - (0.5f - ly) * (0.5f - ly);
        wy[2] = 0.5f * ly * ly;
        wz[0] = 0.5f * (1.0f - lz) * (1.0f - lz);
        wz[1] = 0.75f - (0.5f - lz) * (0.5f - lz);
        wz[2] = 0.5f * lz * lz;

        int rx = bx - obx;             // 0..7
        int ry = by - oby;
        int rz = bz - obz;

        float ox = 0.0f, oy = 0.0f, oz = 0.0f;
#pragma unroll
        for (int a = 0; a < 3; ++a) {
#pragma unroll
            for (int bb = 0; bb < 3; ++bb) {
                const float* pp = &R[((rx + a) * 10 + (ry + bb)) * 30 + rz * 3];
                float wab = wx[a] * wy[bb];
                float w0 = wab * wz[0];
                float w1 = wab * wz[1];
                float w2 = wab * wz[2];
                ox += w0 * pp[0] + w1 * pp[3] + w2 * pp[6];
                oy += w0 * pp[1] + w1 * pp[4] + w2 * pp[7];
                oz += w0 * pp[2] + w1 * pp[5] + w2 * pp[8];
            }
        }

        out[3 * idx + 0] = ox;
        out[3 * idx + 1] = oy;
        out[3 * idx + 2] = oz;
    }
}

// Fallback: naive per-particle gather
__global__ void __launch_bounds__(256) g2p_naive_kernel(
    const float* __restrict__ grid, const float* __restrict__ pos,
    float* __restrict__ out, int n)
{
    int i = blockIdx.x * blockDim.x + threadIdx.x;
    if (i >= n) return;
    float px = pos[3 * i + 0], py = pos[3 * i + 1], pz = pos[3 * i + 2];
    float nx = px * INV_DX, ny = py * INV_DX, nz = pz * INV_DX;
    int bx = (int)nx, by = (int)ny, bz = (int)nz;
    float lx = nx - bx, ly = ny - by, lz = nz - bz;
    float wx[3], wy[3], wz[3];
    wx[0] = 0.5f * (1.0f - lx) * (1.0f - lx);
    wx[1] = 0.75f - (0.5f - lx) * (0.5f - lx);
    wx[2] = 0.5f * lx * lx;
    wy[0] = 0.5f * (1.0f - ly) * (1.0f - ly);
    wy[1] = 0.75f - (0.5f - ly) * (0.5f - ly);
    wy[2] = 0.5f * ly * ly;
    wz[0] = 0.5f * (1.0f - lz) * (1.0f - lz);
    wz[1] = 0.75f - (0.5f - lz) * (0.5f - lz);
    wz[2] = 0.5f * lz * lz;
    const int s1 = N_GRID * 3, s0 = N_GRID * N_GRID * 3;
    const float* gbase = grid + (long)bx * s0 + by * s1 + bz * 3;
    float ox = 0, oy = 0, oz = 0;
#pragma unroll
    for (int a = 0; a < 3; ++a)
#pragma unroll
        for (int b = 0; b < 3; ++b) {
            const float* pp = gbase + a * s0 + b * s1;
            float wab = wx[a] * wy[b];
            float w0 = wab * wz[0], w1 = wab * wz[1], w2 = wab * wz[2];
            ox += w0 * pp[0] + w1 * pp[3] + w2 * pp[6];
            oy += w0 * pp[1] + w1 * pp[4] + w2 * pp[7];
            oz += w0 * pp[2] + w1 * pp[5] + w2 * pp[8];
        }
    out[3 * i + 0] = ox;
    out[3 * i + 1] = oy;
    out[3 * i + 2] = oz;
}

extern "C" void kernel_launch(void* const* d_in, const int* in_sizes, int n_in,
                              void* d_out, int out_size, void* d_ws, size_t ws_size,
                              hipStream_t stream) {
    const float* grid = (const float*)d_in[0];
    const float* pos  = (const float*)d_in[1];
    float* out        = (float*)d_out;
    int n = in_sizes[1] / 3;

    int block = 256;
    int blocks = (n + block - 1) / block;
    int blocksK = (n + block * KP - 1) / (block * KP);

    // ws layout: [0,16K) hist | [16K,32K) offs | [256K, 256K+2n) bin12 |
    //            [align256, +16n) coarse
    size_t bin_off = 256u << 10;
    size_t coarse_off = (bin_off + (size_t)n * 2 + 255) & ~(size_t)255;
    size_t need = coarse_off + (size_t)n * sizeof(float4);

    if (ws_size < need) {
        g2p_naive_kernel<<<blocks, block, 0, stream>>>(grid, pos, out, n);
        return;
    }

    unsigned int* hist = (unsigned int*)d_ws;
    unsigned int* offs = hist + NSUPER;
    unsigned short* bin12 = (unsigned short*)((char*)d_ws + bin_off);
    float4* coarse = (float4*)((char*)d_ws + coarse_off);

    hipMemsetAsync(hist, 0, NSUPER * sizeof(unsigned int), stream);
    binify_kernel<<<blocksK, block, 0, stream>>>(pos, bin12, n);
    hist8_kernel<<<blocksK * 8, block, 0, stream>>>(bin12, hist, n);
    scan_kernel<<<1, SCAN_THREADS, 0, stream>>>(hist, offs);
    scatter8_kernel<<<blocksK * 8, block, 0, stream>>>(pos, bin12, coarse, offs, n);
    gather_super_kernel<<<NSUPER, block, 0, stream>>>(grid, coarse, offs, hist, out);
}

// Round 10
// 450.662 us; speedup vs baseline: 1.8226x; 1.8226x over previous
//
#include <hip/hip_runtime.h>

#define N_GRID 144
#define INV_DX 128.0f
#define NBINS 32768          // 32 x 32 x 32 bins of 4^3 cells
#define PAD 16               // one 64B cache line per atomic counter
#define SCAN_THREADS 1024
#define PER_THREAD 32        // 1024 * 32 = 32768
#define KP 8                 // particles per thread in streaming passes

__device__ __forceinline__ int bin_of(float px, float py, float pz) {
    int bx = (int)(px * INV_DX);   // 0..127
    int by = (int)(py * INV_DX);
    int bz = (int)(pz * INV_DX);
    return ((bx >> 2) << 10) | ((by >> 2) << 5) | (bz >> 2);
}

// Pass 0: bin16[i] = bin index (coalesced read/write, no atomics)
__global__ void __launch_bounds__(256) binify_kernel(
    const float* __restrict__ pos, unsigned short* __restrict__ bin16, int n)
{
    int base = blockIdx.x * (blockDim.x * KP) + threadIdx.x;
#pragma unroll
    for (int k = 0; k < KP; ++k) {
        int p = base + k * 256;
        if (p < n) {
            float px = pos[3 * p + 0];
            float py = pos[3 * p + 1];
            float pz = pos[3 * p + 2];
            bin16[p] = (unsigned short)bin_of(px, py, pz);
        }
    }
}

// Pass 1: octant-filtered histogram; atomics XCD-local (bin>>12 = x-octant)
// AND line-exclusive (PAD): no same-line serialization.
__global__ void __launch_bounds__(256) hist8_kernel(
    const unsigned short* __restrict__ bin16, unsigned int* __restrict__ hist_pad, int n)
{
    int owner = blockIdx.x & 7;
    int chunk = blockIdx.x >> 3;
    int base = chunk * (256 * KP) + threadIdx.x;
    int bn[KP], ok[KP];
#pragma unroll
    for (int k = 0; k < KP; ++k) {
        int p = base + k * 256;
        ok[k] = (p < n);
        bn[k] = bin16[ok[k] ? p : 0];
        ok[k] = ok[k] && ((bn[k] >> 12) == owner);
    }
#pragma unroll
    for (int k = 0; k < KP; ++k) {
        if (ok[k]) atomicAdd(&hist_pad[bn[k] * PAD], 1u);
    }
}

// Scan over padded counters (reads/writes stride-PAD).
__global__ void __launch_bounds__(SCAN_THREADS) scan_kernel(
    const unsigned int* __restrict__ hist_pad, unsigned int* __restrict__ offs_pad)
{
    __shared__ unsigned int partial[SCAN_THREADS];
    int t = threadIdx.x;
    unsigned int local[PER_THREAD];
    unsigned int s = 0;
    int base = t * PER_THREAD;
#pragma unroll
    for (int k = 0; k < PER_THREAD; ++k) {
        local[k] = s;
        s += hist_pad[(base + k) * PAD];
    }
    partial[t] = s;
    __syncthreads();
    for (int d = 1; d < SCAN_THREADS; d <<= 1) {
        unsigned int v = (t >= d) ? partial[t - d] : 0u;
        __syncthreads();
        partial[t] += v;
        __syncthreads();
    }
    unsigned int chunk_excl = (t == 0) ? 0u : partial[t - 1];
#pragma unroll
    for (int k = 0; k < PER_THREAD; ++k)
        offs_pad[(base + k) * PAD] = chunk_excl + local[k];
}

// Pass 2: octant-filtered scatter; dense coalesced pos reads; atomics
// XCD-local + line-exclusive; sorted-line writers all on one XCD.
__global__ void __launch_bounds__(256) scatter8_kernel(
    const float* __restrict__ pos, const unsigned short* __restrict__ bin16,
    float4* __restrict__ sorted, unsigned int* __restrict__ offs_pad, int n)
{
    int owner = blockIdx.x & 7;
    int chunk = blockIdx.x >> 3;
    int base = chunk * (256 * KP) + threadIdx.x;
    float px[KP], py[KP], pz[KP];
    int bn[KP], ok[KP];
#pragma unroll
    for (int k = 0; k < KP; ++k) {
        int p = base + k * 256;
        ok[k] = (p < n);
        int q = ok[k] ? p : 0;
        px[k] = pos[3 * q + 0];
        py[k] = pos[3 * q + 1];
        pz[k] = pos[3 * q + 2];
        bn[k] = bin16[q];
        ok[k] = ok[k] && ((bn[k] >> 12) == owner);
    }
    unsigned int off[KP];
#pragma unroll
    for (int k = 0; k < KP; ++k) {
        if (ok[k]) off[k] = atomicAdd(&offs_pad[bn[k] * PAD], 1u);
    }
#pragma unroll
    for (int k = 0; k < KP; ++k) {
        if (ok[k]) {
            int p = base + k * 256;
            float4 v;
            v.x = px[k]; v.y = py[k]; v.z = pz[k];
            v.w = __int_as_float(p);
            sorted[off[k]] = v;
        }
    }
}

// Pass 3: bin-centric gather. One 128-thread block per bin; 6x6x6-node
// stencil (648 floats, 2.6KB) staged to LDS; 27 taps served from LDS.
// Octant-swizzled (b>>12 == blockIdx&7) for per-XCD grid slab locality.
__global__ void __launch_bounds__(128) gather_bin_kernel(
    const float* __restrict__ grid,
    const float4* __restrict__ sorted,
    const unsigned int* __restrict__ offs_pad,
    const unsigned int* __restrict__ hist_pad,
    float* __restrict__ out)
{
    int b = (blockIdx.x & 7) * 4096 + (blockIdx.x >> 3);   // bijective, 32768=8*4096

    unsigned int end = offs_pad[b * PAD];
    unsigned int cnt = hist_pad[b * PAD];
    if (cnt == 0) return;
    unsigned int start = end - cnt;

    int obx = 4 * (b >> 10);
    int oby = 4 * ((b >> 5) & 31);
    int obz = 4 * (b & 31);

    const int s1 = N_GRID * 3;
    const int s0 = N_GRID * N_GRID * 3;

    __shared__ float R[648];          // [6][6][18]
    const float* gorig = grid + (long)obx * s0 + oby * s1 + obz * 3;
    int tid = threadIdx.x;
#pragma unroll
    for (int f = tid; f < 648; f += 128) {
        int row = f / 18;
        int zz = f - row * 18;
        R[f] = gorig[(row / 6) * s0 + (row % 6) * s1 + zz];
    }
    __syncthreads();

    for (unsigned int j = start + tid; j < end; j += 128) {
        float4 p = sorted[j];
        int idx = __float_as_int(p.w);

        float nx = p.x * INV_DX;
        float ny = p.y * INV_DX;
        float nz = p.z * INV_DX;
        int bx = (int)nx;
        int by = (int)ny;
        int bz = (int)nz;
        float lx = nx - (float)bx;
        float ly = ny - (float)by;
        float lz = nz - (float)bz;

        float wx[3], wy[3], wz[3];
        wx[0] = 0.5f * (1.0f - lx) * (1.0f - lx);
        wx[1] = 0.75f - (0.5f - lx) * (0.5f - lx);
        wx[2] = 0.5f * lx * lx;
        wy[0] = 0.5f * (1.0f - ly) * (1.0f - ly);
        wy[1] = 0.75f - (0.5f - ly) * (0.5f - ly);
        wy[2] = 0.5f * ly * ly;
        wz[0] = 0.5f * (1.0f - lz) * (1.0f - lz);
        wz[1] = 0.75f - (0.5f - lz) * (0.5f - lz);
        wz[2] = 0.5f * lz * lz;

        int rx = bx - obx;
        int ry = by - oby;
        int rz = bz - obz;

        float ox = 0.0f, oy = 0.0f, oz = 0.0f;
#pragma unroll
        for (int a = 0; a < 3; ++a) {
#pragma unroll
            for (int bb = 0; bb < 3; ++bb) {
                const float* pp = &R[((rx + a) * 6 + (ry + bb)) * 18 + rz * 3];
                float wab = wx[a] * wy[bb];
                float w0 = wab * wz[0];
                float w1 = wab * wz[1];
                float w2 = wab * wz[2];
                ox += w0 * pp[0] + w1 * pp[3] + w2 * pp[6];
                oy += w0 * pp[1] + w1 * pp[4] + w2 * pp[7];
                oz += w0 * pp[2] + w1 * pp[5] + w2 * pp[8];
            }
        }

        out[3 * idx + 0] = ox;
        out[3 * idx + 1] = oy;
        out[3 * idx + 2] = oz;
    }
}

// Fallback: naive per-particle gather
__global__ void __launch_bounds__(256) g2p_naive_kernel(
    const float* __restrict__ grid, const float* __restrict__ pos,
    float* __restrict__ out, int n)
{
    int i = blockIdx.x * blockDim.x + threadIdx.x;
    if (i >= n) return;
    float px = pos[3 * i + 0], py = pos[3 * i + 1], pz = pos[3 * i + 2];
    float nx = px * INV_DX, ny = py * INV_DX, nz = pz * INV_DX;
    int bx = (int)nx, by = (int)ny, bz = (int)nz;
    float lx = nx - bx, ly = ny - by, lz = nz - bz;
    float wx[3], wy[3], wz[3];
    wx[0] = 0.5f * (1.0f - lx) * (1.0f - lx);
    wx[1] = 0.75f - (0.5f - lx) * (0.5f - lx);
    wx[2] = 0.5f * lx * lx;
    wy[0] = 0.5f * (1.0f - ly) * (1.0f - ly);
    wy[1] = 0.75f - (0.5f - ly) * (0.5f - ly);
    wy[2] = 0.5f * ly * ly;
    wz[0] = 0.5f * (1.0f - lz) * (1.0f - lz);
    wz[1] = 0.75f - (0.5f - lz) * (0.5f - lz);
    wz[2] = 0.5f * lz * lz;
    const int s1 = N_GRID * 3, s0 = N_GRID * N_GRID * 3;
    const float* gbase = grid + (long)bx * s0 + by * s1 + bz * 3;
    float ox = 0, oy = 0, oz = 0;
#pragma unroll
    for (int a = 0; a < 3; ++a)
#pragma unroll
        for (int b = 0; b < 3; ++b) {
            const float* pp = gbase + a * s0 + b * s1;
            float wab = wx[a] * wy[b];
            float w0 = wab * wz[0], w1 = wab * wz[1], w2 = wab * wz[2];
            ox += w0 * pp[0] + w1 * pp[3] + w2 * pp[6];
            oy += w0 * pp[1] + w1 * pp[4] + w2 * pp[7];
            oz += w0 * pp[2] + w1 * pp[5] + w2 * pp[8];
        }
    out[3 * i + 0] = ox;
    out[3 * i + 1] = oy;
    out[3 * i + 2] = oz;
}

extern "C" void kernel_launch(void* const* d_in, const int* in_sizes, int n_in,
                              void* d_out, int out_size, void* d_ws, size_t ws_size,
                              hipStream_t stream) {
    const float* grid = (const float*)d_in[0];
    const float* pos  = (const float*)d_in[1];
    float* out        = (float*)d_out;
    int n = in_sizes[1] / 3;

    int block = 256;
    int blocks = (n + block - 1) / block;
    int blocksK = (n + block * KP - 1) / (block * KP);

    // ws layout: [0,2M) hist_pad | [2M,4M) offs_pad | [4M, 4M+2n) bin16 |
    //            [align256, +16n) sorted
    size_t hist_bytes = (size_t)NBINS * PAD * sizeof(unsigned int);   // 2 MB
    size_t bin_off = 2 * hist_bytes;
    size_t sorted_off = (bin_off + (size_t)n * 2 + 255) & ~(size_t)255;
    size_t need = sorted_off + (size_t)n * sizeof(float4);

    if (ws_size < need) {
        g2p_naive_kernel<<<blocks, block, 0, stream>>>(grid, pos, out, n);
        return;
    }

    unsigned int* hist_pad = (unsigned int*)d_ws;
    unsigned int* offs_pad = (unsigned int*)((char*)d_ws + hist_bytes);
    unsigned short* bin16 = (unsigned short*)((char*)d_ws + bin_off);
    float4* sorted = (float4*)((char*)d_ws + sorted_off);

    hipMemsetAsync(hist_pad, 0, hist_bytes, stream);
    binify_kernel<<<blocksK, block, 0, stream>>>(pos, bin16, n);
    hist8_kernel<<<blocksK * 8, block, 0, stream>>>(bin16, hist_pad, n);
    scan_kernel<<<1, SCAN_THREADS, 0, stream>>>(hist_pad, offs_pad);
    scatter8_kernel<<<blocksK * 8, block, 0, stream>>>(pos, bin16, sorted, offs_pad, n);
    gather_bin_kernel<<<NBINS, 128, 0, stream>>>(grid, sorted, offs_pad, hist_pad, out);
}